// Round 11
// baseline (192.020 us; speedup 1.0000x reference)
//
#include <hip/hip_runtime.h>
#include <math.h>

#define B_ 2
#define S_ 2048
#define D_ 1024
#define H_ 16
#define DK_ 64
#define M_ (B_ * S_)     // 4096
#define N3_ (3 * D_)     // 3072

typedef __bf16 bf16;
typedef bf16 bf16x4 __attribute__((ext_vector_type(4)));
typedef bf16 bf16x8 __attribute__((ext_vector_type(8)));
typedef float f32x4 __attribute__((ext_vector_type(4)));
typedef short shortx4 __attribute__((ext_vector_type(4)));

// async global->LDS, 16B per lane; LDS dest = wave-uniform base + lane*16
#define GLL16(g, l)                                                     \
  __builtin_amdgcn_global_load_lds(                                     \
      (const __attribute__((address_space(1))) void*)(g),               \
      (__attribute__((address_space(3))) void*)(l), 16, 0, 0)

// Q pre-scale: 1/sqrt(64) * log2(e), so attention uses exp2 directly.
#define QSCALE 0.1803368801111204f

// Workspace (bytes):
//  xb      @ 0        8 MB   bf16 x [4096,1024]
//  Wqkv_bt @ 8 MB     6 MB   bf16 W_qkv^T [3072,1024]
//  Wo_bt   @ 14 MB    2 MB   bf16 W_o^T   [1024,1024]
//  Qb      @ 16 MB    8 MB   bf16 [B,H,S,64] (post-RoPE, PRE-SCALED by QSCALE)
//  Kb      @ 24 MB    8 MB   bf16 [B,H,S,64] (post-RoPE)
//  VTb     @ 32 MB    8 MB   bf16 [B,H,64,S]  (V pre-transposed)
//  AOb     @ 40 MB    8 MB   bf16 [B,S,D]

// ---------------------------------------------------------------------------
// fused prep: cast x | transpose+cast Wqkv | transpose+cast Wo.
// ---------------------------------------------------------------------------
__global__ __launch_bounds__(256) void prep_k(
    const float* __restrict__ x, const float* __restrict__ Wqkv,
    const float* __restrict__ Wo, bf16* __restrict__ xb,
    bf16* __restrict__ Wqkv_bt, bf16* __restrict__ Wo_bt) {
  const int bx = blockIdx.x;
  if (bx < 4096) {  // cast x
    int i = bx * 256 + threadIdx.x;
    float4 v = ((const float4*)x)[i];
    bf16x4 o = {(bf16)v.x, (bf16)v.y, (bf16)v.z, (bf16)v.w};
    ((bf16x4*)xb)[i] = o;
    return;
  }
  __shared__ float t[32][33];
  const float* src;
  bf16* dst;
  int R, C, cx, cy;
  if (bx < 4096 + 3072) {  // Wqkv^T
    int b2 = bx - 4096;
    src = Wqkv; dst = Wqkv_bt; R = D_; C = N3_;
    cx = b2 % 96; cy = b2 / 96;
  } else {                 // Wo^T
    int b2 = bx - 7168;
    src = Wo; dst = Wo_bt; R = D_; C = D_;
    cx = b2 & 31; cy = b2 >> 5;
  }
  int r0 = cy * 32, c0 = cx * 32;
  int tx = threadIdx.x & 31, ty = threadIdx.x >> 5;
#pragma unroll
  for (int rr = 0; rr < 32; rr += 8)
    t[ty + rr][tx] = src[(size_t)(r0 + ty + rr) * C + c0 + tx];
  __syncthreads();
#pragma unroll
  for (int rr = 0; rr < 32; rr += 8)
    dst[(size_t)(c0 + ty + rr) * R + r0 + tx] = (bf16)t[tx][ty + rr];
}

// ---------------------------------------------------------------------------
// MFMA GEMM core (m97 recipe): C[4096 x N] = A[4096x1024] * Bt[N x 1024]^T.
// ---------------------------------------------------------------------------
#define GEMM_KLOOP(A, Bt, KDIM)                                              \
  __shared__ bf16 As[128 * 32];                                              \
  __shared__ bf16 Bs[128 * 32];                                              \
  const int tid = threadIdx.x;                                               \
  const int wave = tid >> 6, lane = tid & 63;                                \
  const int l15 = lane & 15, quad = lane >> 4;                               \
  const int wr = wave >> 1, wc = wave & 1;                                   \
  const int row0 = blockIdx.y * 128, col0 = blockIdx.x * 128;                \
  const int srow = (wave * 128 + lane) >> 2; /* +j*16 */                     \
  const int skc8 = (lane & 3) * 8;                                           \
  f32x4 acc[4][4] = {};                                                      \
  for (int k0 = 0; k0 < KDIM; k0 += 32) {                                    \
    __syncthreads();                                                         \
    _Pragma("unroll") for (int j = 0; j < 2; ++j) {                          \
      GLL16(A + (size_t)(row0 + srow + j * 16) * KDIM + k0 + skc8,           \
            &As[(wave * 128 + j * 64) * 8]);                                 \
      GLL16(Bt + (size_t)(col0 + srow + j * 16) * KDIM + k0 + skc8,          \
            &Bs[(wave * 128 + j * 64) * 8]);                                 \
    }                                                                        \
    __syncthreads();                                                         \
    bf16x8 af[4], bfr[4];                                                    \
    _Pragma("unroll") for (int i = 0; i < 4; ++i)                            \
        af[i] = *(const bf16x8*)&As[(wr * 64 + i * 16 + l15) * 32 + quad * 8]; \
    _Pragma("unroll") for (int t = 0; t < 4; ++t)                            \
        bfr[t] = *(const bf16x8*)&Bs[(wc * 64 + t * 16 + l15) * 32 + quad * 8]; \
    _Pragma("unroll") for (int i = 0; i < 4; ++i)                            \
        _Pragma("unroll") for (int t = 0; t < 4; ++t)                        \
            acc[i][t] = __builtin_amdgcn_mfma_f32_16x16x32_bf16(             \
                af[i], bfr[t], acc[i][t], 0, 0, 0);                          \
  }

// ---------------------------------------------------------------------------
// QKV GEMM. Epilogue via per-wave LDS tile -> coalesced vector stores (r9).
// RoPE computed with __sinf/__cosf (table experiment regressed: r10).
// ---------------------------------------------------------------------------
__global__ __launch_bounds__(256) void gemm_qkv_mfma(
    const bf16* __restrict__ A, const bf16* __restrict__ Bt,
    bf16* __restrict__ Qb, bf16* __restrict__ Kb, bf16* __restrict__ VTb) {
  __shared__ bf16 Ct[4][32 * 72];  // 4608 B per wave (== 64*36 for V)
  GEMM_KLOOP(A, Bt, 1024)

  const int nb = col0 + wc * 64;    // 64-aligned head block
  const int which = nb >> 10;       // 0=Q 1=K 2=V
  const int h = (nb >> 6) & 15;
  const float qsc = (which == 0) ? QSCALE : 1.0f;
  float freq[2];
#pragma unroll
  for (int t = 0; t < 2; ++t)
    freq[t] = exp2f((float)(t * 16 + l15) * -0.4152410118609203f);

  bf16* W = Ct[wave];
  const int mbase0 = row0 + wr * 64;
  const int bb = mbase0 >> 11;  // batch (block never straddles)

#pragma unroll
  for (int ih = 0; ih < 2; ++ih) {
    __syncthreads();  // region free (k-loop LDS or previous reads done)
    if (which == 2) {
      // ---- V: write transposed [d][s_local], stride 36 ----
#pragma unroll
      for (int i2 = 0; i2 < 2; ++i2) {
        int i = ih * 2 + i2;
#pragma unroll
        for (int r = 0; r < 4; ++r) {
          int sl = i2 * 16 + quad * 4 + r;
#pragma unroll
          for (int t = 0; t < 4; ++t)
            W[(t * 16 + l15) * 36 + sl] = (bf16)acc[i][t][r];
        }
      }
    } else {
      // ---- Q/K: RoPE, write [m_local][d], stride 72 ----
#pragma unroll
      for (int i2 = 0; i2 < 2; ++i2) {
        int i = ih * 2 + i2;
#pragma unroll
        for (int r = 0; r < 4; ++r) {
          int ml = i2 * 16 + quad * 4 + r;
          int s = (mbase0 + i * 16 + quad * 4 + r) & (S_ - 1);
#pragma unroll
          for (int t = 0; t < 2; ++t) {
            float theta = (float)s * freq[t];
            float sn = __sinf(theta), cs = __cosf(theta);
            float x1 = acc[i][t][r], x2 = acc[i][t + 2][r];
            W[ml * 72 + t * 16 + l15] = (bf16)((x1 * cs - x2 * sn) * qsc);
            W[ml * 72 + t * 16 + l15 + 32] = (bf16)((x2 * cs + x1 * sn) * qsc);
          }
        }
      }
    }
    __syncthreads();
    const int s0 = (mbase0 + ih * 32) & (S_ - 1);
    if (which == 2) {
      bf16* vbase = VTb + ((size_t)(bb * H_ + h) * DK_) * (size_t)S_ + s0;
#pragma unroll
      for (int rr = 0; rr < 8; ++rr) {
        int d = rr * 8 + (lane >> 3);
        int c4 = (lane & 7) * 4;
        bf16x4 v = *(const bf16x4*)&W[d * 36 + c4];
        *(bf16x4*)(vbase + (size_t)d * S_ + c4) = v;
      }
    } else {
      bf16* basep = ((which == 0) ? Qb : Kb) +
                    (((size_t)(bb * H_ + h) * S_) + s0) * DK_;
#pragma unroll
      for (int rr = 0; rr < 4; ++rr) {
        int row = rr * 8 + (lane >> 3);
        int c8 = (lane & 7) * 8;
        bf16x8 v = *(const bf16x8*)&W[row * 72 + c8];
        *(bf16x8*)(basep + (size_t)row * DK_ + c8) = v;
      }
    }
  }
}

// O-proj GEMM: plain fp32 output [4096,1024]
__global__ __launch_bounds__(256) void gemm_oproj_mfma(
    const bf16* __restrict__ A, const bf16* __restrict__ Bt,
    float* __restrict__ C) {
  GEMM_KLOOP(A, Bt, 1024)
#pragma unroll
  for (int i = 0; i < 4; ++i) {
#pragma unroll
    for (int r = 0; r < 4; ++r) {
      int m = row0 + wr * 64 + i * 16 + quad * 4 + r;
      float* dst = C + (size_t)m * D_ + col0 + wc * 64;
#pragma unroll
      for (int t = 0; t < 4; ++t) dst[t * 16 + l15] = acc[i][t][r];
    }
  }
}

// ---------------------------------------------------------------------------
// MFMA flash attention, S^T formulation, 32 q per wave (2 q-sets share each
// K/V fragment read -> DS per q halves vs r9). Block = 4 waves x 32q = 128 q
// -> 512 blocks. Q pre-scaled by QSCALE so softmax is p = exp2(st).
// Ks stride 72 (144 B, b128 16B-aligned); Vs stride 68 (b64-aligned, free).
// Waves fully below a tile skip compute (barriers already passed).
// ---------------------------------------------------------------------------
__global__ __launch_bounds__(256) void attn_mfma(const bf16* __restrict__ Qb,
                                                 const bf16* __restrict__ Kb,
                                                 const bf16* __restrict__ VT,
                                                 bf16* __restrict__ Out) {
  __shared__ bf16 Ks[64 * 72];
  __shared__ bf16 Vs[64 * 68];

  const int tid = threadIdx.x;
  const int wave = tid >> 6, lane = tid & 63;
  const int l15 = lane & 15, quad = lane >> 4;

  const int bh = blockIdx.x & 31;                  // head-major inner
  const int q0 = (15 - (blockIdx.x >> 5)) * 128;   // longest blocks first
  const int qw = q0 + wave * 32;                   // wave's 32 q rows
  const size_t bh_off = (size_t)bh * (S_ * DK_);

  // Q^T fragments in registers: B[k=dk=32c+quad*8+j][n=q=qw+16s+l15]
  bf16x8 qf[2][2];
#pragma unroll
  for (int s = 0; s < 2; ++s) {
    const bf16* qp = Qb + bh_off + (size_t)(qw + 16 * s + l15) * DK_ + quad * 8;
    qf[s][0] = *(const bf16x8*)qp;
    qf[s][1] = *(const bf16x8*)(qp + 32);
  }

  f32x4 o_acc[2][4] = {};  // [s][u]: O[q=qw+16s+quad*4+r][d=16u+l15]
  float lsum[2] = {};      // partial l for q = qw+16s+l15

  const int kn = q0 + 128;
  for (int k0 = 0; k0 < kn; k0 += 64) {
    __syncthreads();  // prior tile's LDS reads done before restage
#pragma unroll
    for (int it = 0; it < 2; ++it) {
      int e = tid + it * 256;  // 512 chunks of 8 bf16 per array
      int row = e >> 3, c8 = (e & 7) * 8;
      *(bf16x8*)&Ks[row * 72 + c8] =
          *(const bf16x8*)(Kb + bh_off + (size_t)(k0 + row) * DK_ + c8);
      *(bf16x8*)&Vs[row * 68 + c8] =
          *(const bf16x8*)(VT + bh_off + (size_t)row * S_ + k0 + c8);
    }
    __syncthreads();

    if (k0 > qw + 31) continue;      // wave fully masked for this tile
    const bool dm = (k0 + 64 > qw);  // tile overlaps wave's diagonal

    // ---- S^T = K Q^T : 4 key-subtiles x 2 dk-chunks x 2 q-sets ----
    f32x4 st[2][4] = {};
#pragma unroll
    for (int t = 0; t < 4; ++t) {
      const bf16* kr = &Ks[(t * 16 + l15) * 72 + quad * 8];
      bf16x8 kf0 = *(const bf16x8*)kr;
      bf16x8 kf1 = *(const bf16x8*)(kr + 32);
#pragma unroll
      for (int s = 0; s < 2; ++s) {
        st[s][t] = __builtin_amdgcn_mfma_f32_16x16x32_bf16(kf0, qf[s][0],
                                                           st[s][t], 0, 0, 0);
        st[s][t] = __builtin_amdgcn_mfma_f32_16x16x32_bf16(kf1, qf[s][1],
                                                           st[s][t], 0, 0, 0);
      }
    }

    // ---- P^T = exp2(S^T) (Q pre-scaled; mask on diagonal tiles) ----
    bf16x4 pT[2][4];
#pragma unroll
    for (int s = 0; s < 2; ++s) {
      const int q = qw + 16 * s + l15;
#pragma unroll
      for (int t = 0; t < 4; ++t) {
#pragma unroll
        for (int r = 0; r < 4; ++r) {
          int key = k0 + t * 16 + quad * 4 + r;
          float p = __builtin_amdgcn_exp2f(st[s][t][r]);
          if (dm) p = (key <= q) ? p : 0.0f;
          lsum[s] += p;
          pT[s][t][r] = (bf16)p;
        }
      }
    }

    // ---- O += P V : A = P (regs), B = V^T (LDS b64, shared by q-sets) ----
#pragma unroll
    for (int u = 0; u < 4; ++u) {
#pragma unroll
      for (int t = 0; t < 4; ++t) {
        bf16x4 vf = *(const bf16x4*)&Vs[(u * 16 + l15) * 68 + t * 16 + quad * 4];
        shortx4 vs = __builtin_bit_cast(shortx4, vf);
#pragma unroll
        for (int s = 0; s < 2; ++s) {
          o_acc[s][u] = __builtin_amdgcn_mfma_f32_16x16x16bf16_1k(
              __builtin_bit_cast(shortx4, pT[s][t]), vs, o_acc[s][u], 0, 0, 0);
        }
      }
    }
  }

  // ---- epilogue: reduce l over quads, fetch own rows' l, write bf16 ----
  const int b = bh >> 4, h = bh & 15;
#pragma unroll
  for (int s = 0; s < 2; ++s) {
    float l = lsum[s];
    l += __shfl_xor(l, 16, 64);
    l += __shfl_xor(l, 32, 64);  // all quads now hold l(q=qw+16s+l15)
#pragma unroll
    for (int r = 0; r < 4; ++r) {
      float inv = 1.0f / __shfl(l, quad * 4 + r, 64);
      int q = qw + 16 * s + quad * 4 + r;
      bf16* op = Out + ((size_t)(b * S_ + q)) * D_ + h * DK_;
#pragma unroll
      for (int u = 0; u < 4; ++u)
        op[u * 16 + l15] = (bf16)(o_acc[s][u][r] * inv);
    }
  }
}

extern "C" void kernel_launch(void* const* d_in, const int* in_sizes, int n_in,
                              void* d_out, int out_size, void* d_ws,
                              size_t ws_size, hipStream_t stream) {
  const float* x = (const float*)d_in[0];      // [2,2048,1024]
  const float* Wqkv = (const float*)d_in[1];   // [1024,3072]
  const float* Wo = (const float*)d_in[2];     // [1024,1024]
  float* out = (float*)d_out;

  char* ws = (char*)d_ws;
  bf16* xb = (bf16*)(ws + 0);
  bf16* Wqkv_bt = (bf16*)(ws + (8u << 20));
  bf16* Wo_bt = (bf16*)(ws + (14u << 20));
  bf16* Qb = (bf16*)(ws + (16u << 20));
  bf16* Kb = (bf16*)(ws + (24u << 20));
  bf16* VTb = (bf16*)(ws + (32u << 20));
  bf16* AOb = (bf16*)(ws + (40u << 20));

  // 0) fused prep
  prep_k<<<4096 + 3072 + 1024, 256, 0, stream>>>(x, Wqkv, Wo, xb, Wqkv_bt,
                                                 Wo_bt);

  // 1) QKV projection (MFMA) + RoPE fused; coalesced LDS-staged epilogue
  gemm_qkv_mfma<<<dim3(N3_ / 128, M_ / 128), 256, 0, stream>>>(xb, Wqkv_bt, Qb,
                                                               Kb, VTb);

  // 2) MFMA flash attention (S^T, 32q/wave) -> AOb [B,S,D] bf16
  attn_mfma<<<B_ * H_ * (S_ / 128), 256, 0, stream>>>(Qb, Kb, VTb, AOb);

  // 3) output projection (MFMA) -> d_out fp32
  gemm_oproj_mfma<<<dim3(D_ / 128, M_ / 128), 256, 0, stream>>>(AOb, Wo_bt, out);
}

// Round 12
// 181.494 us; speedup vs baseline: 1.0580x; 1.0580x over previous
//
#include <hip/hip_runtime.h>
#include <math.h>

#define B_ 2
#define S_ 2048
#define D_ 1024
#define H_ 16
#define DK_ 64
#define M_ (B_ * S_)     // 4096
#define N3_ (3 * D_)     // 3072

typedef __bf16 bf16;
typedef bf16 bf16x4 __attribute__((ext_vector_type(4)));
typedef bf16 bf16x8 __attribute__((ext_vector_type(8)));
typedef float f32x4 __attribute__((ext_vector_type(4)));
typedef short shortx4 __attribute__((ext_vector_type(4)));

// async global->LDS, 16B per lane; LDS dest = WAVE-UNIFORM base + lane*16
#define GLL16(g, l)                                                     \
  __builtin_amdgcn_global_load_lds(                                     \
      (const __attribute__((address_space(1))) void*)(g),               \
      (__attribute__((address_space(3))) void*)(l), 16, 0, 0)

// Q pre-scale: 1/sqrt(64) * log2(e), so attention uses exp2 directly.
#define QSCALE 0.1803368801111204f

// Workspace (bytes):
//  xb      @ 0        8 MB   bf16 x [4096,1024]
//  Wqkv_bt @ 8 MB     6 MB   bf16 W_qkv^T [3072,1024]
//  Wo_bt   @ 14 MB    2 MB   bf16 W_o^T   [1024,1024]
//  Qb      @ 16 MB    8 MB   bf16 [B,H,S,64] (post-RoPE, PRE-SCALED by QSCALE)
//  Kb      @ 24 MB    8 MB   bf16 [B,H,S,64] (post-RoPE)
//  VTb     @ 32 MB    8 MB   bf16 [B,H,64,S]  (V pre-transposed)
//  AOb     @ 40 MB    8 MB   bf16 [B,S,D]

// ---------------------------------------------------------------------------
// fused prep: cast x | transpose+cast Wqkv | transpose+cast Wo.
// ---------------------------------------------------------------------------
__global__ __launch_bounds__(256) void prep_k(
    const float* __restrict__ x, const float* __restrict__ Wqkv,
    const float* __restrict__ Wo, bf16* __restrict__ xb,
    bf16* __restrict__ Wqkv_bt, bf16* __restrict__ Wo_bt) {
  const int bx = blockIdx.x;
  if (bx < 4096) {  // cast x
    int i = bx * 256 + threadIdx.x;
    float4 v = ((const float4*)x)[i];
    bf16x4 o = {(bf16)v.x, (bf16)v.y, (bf16)v.z, (bf16)v.w};
    ((bf16x4*)xb)[i] = o;
    return;
  }
  __shared__ float t[32][33];
  const float* src;
  bf16* dst;
  int R, C, cx, cy;
  if (bx < 4096 + 3072) {  // Wqkv^T
    int b2 = bx - 4096;
    src = Wqkv; dst = Wqkv_bt; R = D_; C = N3_;
    cx = b2 % 96; cy = b2 / 96;
  } else {                 // Wo^T
    int b2 = bx - 7168;
    src = Wo; dst = Wo_bt; R = D_; C = D_;
    cx = b2 & 31; cy = b2 >> 5;
  }
  int r0 = cy * 32, c0 = cx * 32;
  int tx = threadIdx.x & 31, ty = threadIdx.x >> 5;
#pragma unroll
  for (int rr = 0; rr < 32; rr += 8)
    t[ty + rr][tx] = src[(size_t)(r0 + ty + rr) * C + c0 + tx];
  __syncthreads();
#pragma unroll
  for (int rr = 0; rr < 32; rr += 8)
    dst[(size_t)(c0 + ty + rr) * R + r0 + tx] = (bf16)t[tx][ty + rr];
}

// ---------------------------------------------------------------------------
// MFMA GEMM core (m97 recipe): C[4096 x N] = A[4096x1024] * Bt[N x 1024]^T.
// 128x128 tile, BK=32, 4 waves 2x2.
// ---------------------------------------------------------------------------
#define GEMM_KLOOP(A, Bt, KDIM)                                              \
  __shared__ bf16 As[128 * 32];                                              \
  __shared__ bf16 Bs[128 * 32];                                              \
  const int tid = threadIdx.x;                                               \
  const int wave = tid >> 6, lane = tid & 63;                                \
  const int l15 = lane & 15, quad = lane >> 4;                               \
  const int wr = wave >> 1, wc = wave & 1;                                   \
  const int row0 = blockIdx.y * 128, col0 = blockIdx.x * 128;                \
  const int srow = (wave * 128 + lane) >> 2; /* +j*16 */                     \
  const int skc8 = (lane & 3) * 8;                                           \
  f32x4 acc[4][4] = {};                                                      \
  for (int k0 = 0; k0 < KDIM; k0 += 32) {                                    \
    __syncthreads();                                                         \
    _Pragma("unroll") for (int j = 0; j < 2; ++j) {                          \
      GLL16(A + (size_t)(row0 + srow + j * 16) * KDIM + k0 + skc8,           \
            &As[(wave * 128 + j * 64) * 8]);                                 \
      GLL16(Bt + (size_t)(col0 + srow + j * 16) * KDIM + k0 + skc8,          \
            &Bs[(wave * 128 + j * 64) * 8]);                                 \
    }                                                                        \
    __syncthreads();                                                         \
    bf16x8 af[4], bfr[4];                                                    \
    _Pragma("unroll") for (int i = 0; i < 4; ++i)                            \
        af[i] = *(const bf16x8*)&As[(wr * 64 + i * 16 + l15) * 32 + quad * 8]; \
    _Pragma("unroll") for (int t = 0; t < 4; ++t)                            \
        bfr[t] = *(const bf16x8*)&Bs[(wc * 64 + t * 16 + l15) * 32 + quad * 8]; \
    _Pragma("unroll") for (int i = 0; i < 4; ++i)                            \
        _Pragma("unroll") for (int t = 0; t < 4; ++t)                        \
            acc[i][t] = __builtin_amdgcn_mfma_f32_16x16x32_bf16(             \
                af[i], bfr[t], acc[i][t], 0, 0, 0);                          \
  }

// ---------------------------------------------------------------------------
// QKV GEMM. Epilogue via per-wave LDS tile -> coalesced vector stores (r9).
// RoPE computed with __sinf/__cosf (table experiment regressed: r10).
// ---------------------------------------------------------------------------
__global__ __launch_bounds__(256) void gemm_qkv_mfma(
    const bf16* __restrict__ A, const bf16* __restrict__ Bt,
    bf16* __restrict__ Qb, bf16* __restrict__ Kb, bf16* __restrict__ VTb) {
  __shared__ bf16 Ct[4][32 * 72];  // 4608 B per wave (== 64*36 for V)
  GEMM_KLOOP(A, Bt, 1024)

  const int nb = col0 + wc * 64;    // 64-aligned head block
  const int which = nb >> 10;       // 0=Q 1=K 2=V
  const int h = (nb >> 6) & 15;
  const float qsc = (which == 0) ? QSCALE : 1.0f;
  float freq[2];
#pragma unroll
  for (int t = 0; t < 2; ++t)
    freq[t] = exp2f((float)(t * 16 + l15) * -0.4152410118609203f);

  bf16* W = Ct[wave];
  const int mbase0 = row0 + wr * 64;
  const int bb = mbase0 >> 11;  // batch (block never straddles)

#pragma unroll
  for (int ih = 0; ih < 2; ++ih) {
    __syncthreads();  // region free (k-loop LDS or previous reads done)
    if (which == 2) {
      // ---- V: write transposed [d][s_local], stride 36 ----
#pragma unroll
      for (int i2 = 0; i2 < 2; ++i2) {
        int i = ih * 2 + i2;
#pragma unroll
        for (int r = 0; r < 4; ++r) {
          int sl = i2 * 16 + quad * 4 + r;
#pragma unroll
          for (int t = 0; t < 4; ++t)
            W[(t * 16 + l15) * 36 + sl] = (bf16)acc[i][t][r];
        }
      }
    } else {
      // ---- Q/K: RoPE, write [m_local][d], stride 72 ----
#pragma unroll
      for (int i2 = 0; i2 < 2; ++i2) {
        int i = ih * 2 + i2;
#pragma unroll
        for (int r = 0; r < 4; ++r) {
          int ml = i2 * 16 + quad * 4 + r;
          int s = (mbase0 + i * 16 + quad * 4 + r) & (S_ - 1);
#pragma unroll
          for (int t = 0; t < 2; ++t) {
            float theta = (float)s * freq[t];
            float sn = __sinf(theta), cs = __cosf(theta);
            float x1 = acc[i][t][r], x2 = acc[i][t + 2][r];
            W[ml * 72 + t * 16 + l15] = (bf16)((x1 * cs - x2 * sn) * qsc);
            W[ml * 72 + t * 16 + l15 + 32] = (bf16)((x2 * cs + x1 * sn) * qsc);
          }
        }
      }
    }
    __syncthreads();
    const int s0 = (mbase0 + ih * 32) & (S_ - 1);
    if (which == 2) {
      bf16* vbase = VTb + ((size_t)(bb * H_ + h) * DK_) * (size_t)S_ + s0;
#pragma unroll
      for (int rr = 0; rr < 8; ++rr) {
        int d = rr * 8 + (lane >> 3);
        int c4 = (lane & 7) * 4;
        bf16x4 v = *(const bf16x4*)&W[d * 36 + c4];
        *(bf16x4*)(vbase + (size_t)d * S_ + c4) = v;
      }
    } else {
      bf16* basep = ((which == 0) ? Qb : Kb) +
                    (((size_t)(bb * H_ + h) * S_) + s0) * DK_;
#pragma unroll
      for (int rr = 0; rr < 4; ++rr) {
        int row = rr * 8 + (lane >> 3);
        int c8 = (lane & 7) * 8;
        bf16x8 v = *(const bf16x8*)&W[row * 72 + c8];
        *(bf16x8*)(basep + (size_t)row * DK_ + c8) = v;
      }
    }
  }
}

// ---------------------------------------------------------------------------
// O-proj GEMM, 64x128 tile -> 512 blocks (2/CU; old 128x128 gave 256 = 1/CU,
// tail-bound). 4 waves side-by-side over 32-col chunks; BK=32.
// A-tile 64x32 = exactly one GLL16 pass; B-tile 128x32 = two.
// ---------------------------------------------------------------------------
__global__ __launch_bounds__(256) void gemm_oproj_mfma(
    const bf16* __restrict__ A, const bf16* __restrict__ Bt,
    float* __restrict__ C) {
  __shared__ bf16 As[64 * 32];
  __shared__ bf16 Bs[128 * 32];
  const int tid = threadIdx.x;
  const int wave = tid >> 6, lane = tid & 63;
  const int l15 = lane & 15, quad = lane >> 4;
  const int row0 = blockIdx.y * 64, col0 = blockIdx.x * 128;
  const int rA = tid >> 2, cA = (tid & 3) * 8;  // A chunk coords
  f32x4 acc[4][2] = {};

  for (int k0 = 0; k0 < 1024; k0 += 32) {
    __syncthreads();
    GLL16(A + (size_t)(row0 + rA) * 1024 + k0 + cA, &As[wave * 512]);
#pragma unroll
    for (int p = 0; p < 2; ++p) {
      int e = tid + p * 256;
      GLL16(Bt + (size_t)(col0 + (e >> 2)) * 1024 + k0 + (e & 3) * 8,
            &Bs[(p * 256 + wave * 64) * 8]);
    }
    __syncthreads();
    bf16x8 af[4], bfr[2];
#pragma unroll
    for (int i = 0; i < 4; ++i)
      af[i] = *(const bf16x8*)&As[(i * 16 + l15) * 32 + quad * 8];
#pragma unroll
    for (int t = 0; t < 2; ++t)
      bfr[t] = *(const bf16x8*)&Bs[(wave * 32 + t * 16 + l15) * 32 + quad * 8];
#pragma unroll
    for (int i = 0; i < 4; ++i)
#pragma unroll
      for (int t = 0; t < 2; ++t)
        acc[i][t] = __builtin_amdgcn_mfma_f32_16x16x32_bf16(af[i], bfr[t],
                                                            acc[i][t], 0, 0, 0);
  }
#pragma unroll
  for (int i = 0; i < 4; ++i) {
#pragma unroll
    for (int r = 0; r < 4; ++r) {
      int m = row0 + i * 16 + quad * 4 + r;
      float* dst = C + (size_t)m * D_ + col0 + wave * 32;
#pragma unroll
      for (int t = 0; t < 2; ++t) dst[t * 16 + l15] = acc[i][t][r];
    }
  }
}

// ---------------------------------------------------------------------------
// MFMA flash attention, S^T formulation, 16q/wave, 1024 blocks (r9 shape —
// r7/r11 both showed block-parallelism beats per-wave DS amortization here),
// + DOUBLE-BUFFERED K/V staging: one barrier per tile (end of iter), next
// tile's global loads issued before current tile's compute so HBM/L2 latency
// hides under MFMA+softmax. LDS 2x(64*72 + 64*68) bf16 = 35.8 KB -> 4
// blocks/CU, which equals the grid's 4 blocks/CU: free.
// Q pre-scaled by QSCALE so softmax is p = exp2(st).
// ---------------------------------------------------------------------------
__global__ __launch_bounds__(256) void attn_mfma(const bf16* __restrict__ Qb,
                                                 const bf16* __restrict__ Kb,
                                                 const bf16* __restrict__ VT,
                                                 bf16* __restrict__ Out) {
  __shared__ bf16 Ks[2][64 * 72];
  __shared__ bf16 Vs[2][64 * 68];

  const int tid = threadIdx.x;
  const int wave = tid >> 6, lane = tid & 63;
  const int l15 = lane & 15, quad = lane >> 4;

  const int bh = blockIdx.x & 31;                  // head-major inner
  const int q0 = (31 - (blockIdx.x >> 5)) * 64;    // longest blocks first
  const int qw = q0 + wave * 16;                   // wave's 16 q rows
  const size_t bh_off = (size_t)bh * (S_ * DK_);

  // staging coords: chunk it covers row rowS+32*it, cols c8S..c8S+7
  const int rowS = tid >> 3, c8S = (tid & 7) * 8;

  // Q^T fragments in registers: B[k=dk=32c+quad*8+j][n=q=qw+l15]
  const bf16* qp = Qb + bh_off + (size_t)(qw + l15) * DK_ + quad * 8;
  bf16x8 qf0 = *(const bf16x8*)qp;        // dk 0..31 slice
  bf16x8 qf1 = *(const bf16x8*)(qp + 32); // dk 32..63 slice

  f32x4 o_acc[4] = {};   // [u]: O[q=qw+quad*4+r][d=16u+l15]
  float lsum = 0.0f;     // partial l for q = qw+l15

  // ---- prologue: stage tile 0 into buffer 0 ----
  bf16x8 kreg[2], vreg[2];
#pragma unroll
  for (int it = 0; it < 2; ++it) {
    int row = rowS + it * 32;
    kreg[it] = *(const bf16x8*)(Kb + bh_off + (size_t)row * DK_ + c8S);
    vreg[it] = *(const bf16x8*)(VT + bh_off + (size_t)row * S_ + c8S);
  }
#pragma unroll
  for (int it = 0; it < 2; ++it) {
    int row = rowS + it * 32;
    *(bf16x8*)&Ks[0][row * 72 + c8S] = kreg[it];
    *(bf16x8*)&Vs[0][row * 68 + c8S] = vreg[it];
  }
  __syncthreads();

  const int ntiles = (q0 >> 6) + 1;
  for (int j = 0; j < ntiles; ++j) {
    const int k0 = j * 64;
    const int cur = j & 1;
    const bool more = (j + 1 < ntiles);

    // ---- prefetch next tile's K/V into regs (latency hides under compute)
    if (more) {
      int k1 = k0 + 64;
#pragma unroll
      for (int it = 0; it < 2; ++it) {
        int row = rowS + it * 32;
        kreg[it] = *(const bf16x8*)(Kb + bh_off + (size_t)(k1 + row) * DK_ + c8S);
        vreg[it] = *(const bf16x8*)(VT + bh_off + (size_t)row * S_ + k1 + c8S);
      }
    }

    const bf16* ksc = Ks[cur];
    const bf16* vsc = Vs[cur];
    const bool dm = (k0 + 64 > qw);  // wave's diagonal tile

    // ---- S^T = K Q^T : 4 key-subtiles x 2 dk-chunks ----
    f32x4 st[4] = {};
#pragma unroll
    for (int t = 0; t < 4; ++t) {
      const bf16* kr = &ksc[(t * 16 + l15) * 72 + quad * 8];
      bf16x8 kf0 = *(const bf16x8*)kr;
      bf16x8 kf1 = *(const bf16x8*)(kr + 32);
      st[t] = __builtin_amdgcn_mfma_f32_16x16x32_bf16(kf0, qf0, st[t], 0, 0, 0);
      st[t] = __builtin_amdgcn_mfma_f32_16x16x32_bf16(kf1, qf1, st[t], 0, 0, 0);
    }

    // ---- P^T = exp2(S^T) (Q pre-scaled; mask on diagonal tile) ----
    bf16x4 pT[4];
    const int q = qw + l15;
#pragma unroll
    for (int t = 0; t < 4; ++t) {
#pragma unroll
      for (int r = 0; r < 4; ++r) {
        int key = k0 + t * 16 + quad * 4 + r;
        float p = __builtin_amdgcn_exp2f(st[t][r]);
        if (dm) p = (key <= q) ? p : 0.0f;
        lsum += p;
        pT[t][r] = (bf16)p;
      }
    }

    // ---- O += P V : A = P (regs), B = V^T (LDS b64) ----
#pragma unroll
    for (int u = 0; u < 4; ++u) {
#pragma unroll
      for (int t = 0; t < 4; ++t) {
        bf16x4 vf = *(const bf16x4*)&vsc[(u * 16 + l15) * 68 + t * 16 + quad * 4];
        o_acc[u] = __builtin_amdgcn_mfma_f32_16x16x16bf16_1k(
            __builtin_bit_cast(shortx4, pT[t]),
            __builtin_bit_cast(shortx4, vf), o_acc[u], 0, 0, 0);
      }
    }

    // ---- write prefetched tile into the other buffer; single barrier ----
    if (more) {
      bf16* ksn = Ks[cur ^ 1];
      bf16* vsn = Vs[cur ^ 1];
#pragma unroll
      for (int it = 0; it < 2; ++it) {
        int row = rowS + it * 32;
        *(bf16x8*)&ksn[row * 72 + c8S] = kreg[it];
        *(bf16x8*)&vsn[row * 68 + c8S] = vreg[it];
      }
      __syncthreads();
    }
  }

  // ---- epilogue: reduce l over quads, fetch own rows' l, write bf16 ----
  const int b = bh >> 4, h = bh & 15;
  float l = lsum;
  l += __shfl_xor(l, 16, 64);
  l += __shfl_xor(l, 32, 64);  // all quads now hold l(q=qw+l15)
#pragma unroll
  for (int r = 0; r < 4; ++r) {
    float inv = 1.0f / __shfl(l, quad * 4 + r, 64);
    int q = qw + quad * 4 + r;
    bf16* op = Out + ((size_t)(b * S_ + q)) * D_ + h * DK_;
#pragma unroll
    for (int u = 0; u < 4; ++u)
      op[u * 16 + l15] = (bf16)(o_acc[u][r] * inv);
  }
}

extern "C" void kernel_launch(void* const* d_in, const int* in_sizes, int n_in,
                              void* d_out, int out_size, void* d_ws,
                              size_t ws_size, hipStream_t stream) {
  const float* x = (const float*)d_in[0];      // [2,2048,1024]
  const float* Wqkv = (const float*)d_in[1];   // [1024,3072]
  const float* Wo = (const float*)d_in[2];     // [1024,1024]
  float* out = (float*)d_out;

  char* ws = (char*)d_ws;
  bf16* xb = (bf16*)(ws + 0);
  bf16* Wqkv_bt = (bf16*)(ws + (8u << 20));
  bf16* Wo_bt = (bf16*)(ws + (14u << 20));
  bf16* Qb = (bf16*)(ws + (16u << 20));
  bf16* Kb = (bf16*)(ws + (24u << 20));
  bf16* VTb = (bf16*)(ws + (32u << 20));
  bf16* AOb = (bf16*)(ws + (40u << 20));

  // 0) fused prep
  prep_k<<<4096 + 3072 + 1024, 256, 0, stream>>>(x, Wqkv, Wo, xb, Wqkv_bt,
                                                 Wo_bt);

  // 1) QKV projection (MFMA) + RoPE fused; coalesced LDS-staged epilogue
  gemm_qkv_mfma<<<dim3(N3_ / 128, M_ / 128), 256, 0, stream>>>(xb, Wqkv_bt, Qb,
                                                               Kb, VTb);

  // 2) MFMA flash attention (S^T, 16q/wave, dbuf) -> AOb [B,S,D] bf16
  attn_mfma<<<B_ * H_ * (S_ / 64), 256, 0, stream>>>(Qb, Kb, VTb, AOb);

  // 3) output projection (MFMA, 64x128 tiles -> 512 blocks) -> d_out fp32
  gemm_oproj_mfma<<<dim3(D_ / 128, M_ / 64), 256, 0, stream>>>(AOb, Wo_bt, out);
}